// Round 3
// baseline (5770.166 us; speedup 1.0000x reference)
//
#include <hip/hip_runtime.h>

typedef unsigned int u32;
typedef unsigned short u16;

#define CBSZ 8192
#define DIMV 512
#define MROWS 32768   // 8*4096

__device__ __forceinline__ float wave_sum(float v) {
#pragma unroll
    for (int m = 1; m < 64; m <<= 1) v += __shfl_xor(v, m);
    return v;
}

// K1: implicit_cb[c][d] = sum_k cb[c][k] * W[d][k]   (fp32 GEMM, 64x64 tiles)
__global__ __launch_bounds__(256) void k1_implicit(const float* __restrict__ cb,
                                                   const float* __restrict__ W,
                                                   float* __restrict__ outp) {
    __shared__ float As[64 * 64];
    __shared__ float Bs[64 * 64];
    const int c0 = blockIdx.x * 64, d0 = blockIdx.y * 64;
    const int tid = threadIdx.x;
    const int tx = tid & 15, ty = tid >> 4;
    float acc[4][4] = {};
    for (int k0 = 0; k0 < DIMV; k0 += 64) {
        __syncthreads();
#pragma unroll
        for (int it = 0; it < 4; ++it) {
            int chunk = tid + 256 * it;   // 0..1023
            int row = chunk >> 4;         // 0..63
            int g = chunk & 15;           // granule (float4)
            int gs = (g ^ (row & 15)) * 4;
            *(float4*)&As[row * 64 + gs] =
                *(const float4*)(cb + (size_t)(c0 + row) * DIMV + k0 + g * 4);
            *(float4*)&Bs[row * 64 + gs] =
                *(const float4*)(W + (size_t)(d0 + row) * DIMV + k0 + g * 4);
        }
        __syncthreads();
#pragma unroll
        for (int k = 0; k < 64; k += 4) {
            const int g = k >> 2;
            float4 a[4], b[4];
#pragma unroll
            for (int i = 0; i < 4; ++i) a[i] = *(float4*)&As[(ty + 16 * i) * 64 + ((g ^ ty) * 4)];
#pragma unroll
            for (int j = 0; j < 4; ++j) b[j] = *(float4*)&Bs[(tx + 16 * j) * 64 + ((g ^ tx) * 4)];
#pragma unroll
            for (int i = 0; i < 4; ++i)
#pragma unroll
                for (int j = 0; j < 4; ++j) {
                    acc[i][j] = fmaf(a[i].x, b[j].x, acc[i][j]);
                    acc[i][j] = fmaf(a[i].y, b[j].y, acc[i][j]);
                    acc[i][j] = fmaf(a[i].z, b[j].z, acc[i][j]);
                    acc[i][j] = fmaf(a[i].w, b[j].w, acc[i][j]);
                }
        }
    }
#pragma unroll
    for (int i = 0; i < 4; ++i)
#pragma unroll
        for (int j = 0; j < 4; ++j)
            outp[(size_t)(c0 + ty + 16 * i) * DIMV + d0 + tx + 16 * j] = acc[i][j];
}

// K2: in-place row l2norm of cbn (8192 x 512 f32). One wave per row.
__global__ __launch_bounds__(256) void k2_normrows(float* __restrict__ cbn) {
    const int row = blockIdx.x * 4 + (threadIdx.x >> 6);
    const int lane = threadIdx.x & 63;
    float* p = cbn + (size_t)row * DIMV + lane * 8;
    float4 v0 = *(float4*)p, v1 = *(float4*)(p + 4);
    float ss = v0.x * v0.x + v0.y * v0.y + v0.z * v0.z + v0.w * v0.w
             + v1.x * v1.x + v1.y * v1.y + v1.z * v1.z + v1.w * v1.w;
    ss = wave_sum(ss);
    float n = fmaxf(sqrtf(ss), 1e-12f);
    v0.x /= n; v0.y /= n; v0.z /= n; v0.w /= n;
    v1.x /= n; v1.y /= n; v1.z /= n; v1.w /= n;
    *(float4*)p = v0;
    *(float4*)(p + 4) = v1;
}

// K3: fused raw-dot (scale-invariant) argmax over all codes, fp32 VALU, with
// fp64 rescore of near-tie rows (|top1-top2| < 1e-5).
// grid MROWS/64 blocks, 512 threads. BM=64 rows, BN=128 codes; xs staged per
// 128-wide k-quarter (32KB), cbs in 64-wide chunks (32KB, XOR-swizzled).
__global__ __launch_bounds__(512, 4) void k3_argmax(const float* __restrict__ x,
                                                    const float* __restrict__ cbn,
                                                    int* __restrict__ idxp,
                                                    float* __restrict__ out_idx) {
    __shared__ float xs[64 * 128];
    __shared__ float cbs[128 * 64];
    const int r0 = blockIdx.x * 64;
    const int tid = threadIdx.x;
    const int tx = tid & 31;          // code lane
    const int ty = tid >> 5;          // 0..15, owns rows ty*4..ty*4+3
    float best[4] = {-1e30f, -1e30f, -1e30f, -1e30f};
    int bidx[4] = {0, 0, 0, 0};

    for (int ct = 0; ct < CBSZ; ct += 128) {
        float acc[4][4] = {};
        for (int qu = 0; qu < 4; ++qu) {
            __syncthreads();
            // stage xs: 64 rows x 128 f32
#pragma unroll
            for (int it = 0; it < 4; ++it) {
                int chunk = tid + 512 * it;   // 0..2047 float4
                int row = chunk >> 5;         // 0..63
                int seg = chunk & 31;         // 0..31
                *(float4*)&xs[row * 128 + seg * 4] =
                    *(const float4*)(x + (size_t)(r0 + row) * DIMV + qu * 128 + seg * 4);
            }
            for (int kb = 0; kb < 128; kb += 64) {
                if (kb) __syncthreads();
                // stage cbs: 128 codes x 64 f32, swizzled granules
#pragma unroll
                for (int it = 0; it < 4; ++it) {
                    int q = tid + 512 * it;   // 0..2047 float4
                    int row = q >> 4;         // 0..127
                    int g = q & 15;
                    float4 v = *(const float4*)&cbn[(size_t)(ct + row) * DIMV + qu * 128 + kb + g * 4];
                    int gs = g ^ (row & 15);
                    *(float4*)&cbs[row * 64 + gs * 4] = v;
                }
                __syncthreads();
#pragma unroll
                for (int k = 0; k < 64; k += 4) {
                    const int g = k >> 2;
                    float4 xv[4];
#pragma unroll
                    for (int i = 0; i < 4; ++i)
                        xv[i] = *(const float4*)&xs[(ty * 4 + i) * 128 + kb + k];
                    float4 cv[4];
#pragma unroll
                    for (int j = 0; j < 4; ++j) {
                        const int c = tx + 32 * j;
                        const int gs = g ^ (c & 15);
                        cv[j] = *(const float4*)&cbs[c * 64 + gs * 4];
                    }
#pragma unroll
                    for (int i = 0; i < 4; ++i)
#pragma unroll
                        for (int j = 0; j < 4; ++j) {
                            acc[i][j] = fmaf(xv[i].x, cv[j].x, acc[i][j]);
                            acc[i][j] = fmaf(xv[i].y, cv[j].y, acc[i][j]);
                            acc[i][j] = fmaf(xv[i].z, cv[j].z, acc[i][j]);
                            acc[i][j] = fmaf(xv[i].w, cv[j].w, acc[i][j]);
                        }
                }
            }
            __syncthreads();
        }
#pragma unroll
        for (int j = 0; j < 4; ++j) {
            const int cg = ct + tx + 32 * j;
#pragma unroll
            for (int i = 0; i < 4; ++i)
                if (acc[i][j] > best[i]) { best[i] = acc[i][j]; bidx[i] = cg; }
        }
    }
    // save per-thread locals, then merge top-1 across the 32 tx lanes
    float lb[4]; int li[4];
#pragma unroll
    for (int i = 0; i < 4; ++i) { lb[i] = best[i]; li[i] = bidx[i]; }
#pragma unroll
    for (int m = 1; m < 32; m <<= 1) {
#pragma unroll
        for (int i = 0; i < 4; ++i) {
            float ov = __shfl_xor(best[i], m);
            int oi = __shfl_xor(bidx[i], m);
            if (ov > best[i] || (ov == best[i] && oi < bidx[i])) { best[i] = ov; bidx[i] = oi; }
        }
    }
    // approximate top-2: max over lanes excluding the winning lane's entry
#pragma unroll
    for (int i = 0; i < 4; ++i) {
        float ex = (li[i] == bidx[i]) ? -1e30f : lb[i];
        int exi = li[i];
#pragma unroll
        for (int m = 1; m < 32; m <<= 1) {
            float ov = __shfl_xor(ex, m);
            int oi = __shfl_xor(exi, m);
            if (ov > ex || (ov == ex && oi < exi)) { ex = ov; exi = oi; }
        }
        // near-tie: fp64 rescore of the two candidates (rare: ~1e-3 of rows)
        if (best[i] - ex < 1e-5f) {
            const int r = r0 + ty * 4 + i;
            const float* xr = x + (size_t)r * DIMV;
            const float* c1 = cbn + (size_t)bidx[i] * DIMV;
            const float* c2 = cbn + (size_t)exi * DIMV;
            double d1 = 0.0, d2 = 0.0;
#pragma unroll
            for (int kk = 0; kk < 16; ++kk) {
                int k = tx * 16 + kk;
                double xv = (double)xr[k];
                d1 += xv * (double)c1[k];
                d2 += xv * (double)c2[k];
            }
#pragma unroll
            for (int m = 1; m < 32; m <<= 1) {
                d1 += __shfl_xor(d1, m);
                d2 += __shfl_xor(d2, m);
            }
            if (d2 > d1 || (d2 == d1 && exi < bidx[i])) bidx[i] = exi;
        }
    }
    if (tx == 0) {
#pragma unroll
        for (int i = 0; i < 4; ++i) {
            int r = r0 + ty * 4 + i;
            idxp[r] = bidx[i];
            out_idx[r] = (float)bidx[i];
        }
    }
}

// K4: per-row gather + rotation trick + commit-loss partial. One wave per row.
__global__ __launch_bounds__(256) void k4_rotate(const float* __restrict__ x,
                                                 const float* __restrict__ cbn,
                                                 const int* __restrict__ idxp,
                                                 float* __restrict__ outq,
                                                 float* __restrict__ lossp) {
    const int row = blockIdx.x * 4 + (threadIdx.x >> 6);
    const int lane = threadIdx.x & 63;
    const float* xp = x + (size_t)row * DIMV + lane * 8;
    float4 a0 = *(const float4*)xp, a1 = *(const float4*)(xp + 4);
    float xf[8] = {a0.x, a0.y, a0.z, a0.w, a1.x, a1.y, a1.z, a1.w};
    float ss = 0.f;
#pragma unroll
    for (int i = 0; i < 8; ++i) ss += xf[i] * xf[i];
    ss = wave_sum(ss);
    float nx = fmaxf(sqrtf(ss), 1e-12f);
    float s[8];
#pragma unroll
    for (int i = 0; i < 8; ++i) s[i] = xf[i] / nx;   // x_norm
    int ci = idxp[row];
    ci = ci < 0 ? 0 : (ci > CBSZ - 1 ? CBSZ - 1 : ci);   // defensive clamp
    const float* tp = cbn + (size_t)ci * DIMV + lane * 8;
    float4 t0 = *(const float4*)tp, t1 = *(const float4*)(tp + 4);
    float t[8] = {t0.x, t0.y, t0.z, t0.w, t1.x, t1.y, t1.z, t1.w};
    float ns2 = 0.f, nt2 = 0.f;
#pragma unroll
    for (int i = 0; i < 8; ++i) { ns2 += s[i] * s[i]; nt2 += t[i] * t[i]; }
    ns2 = wave_sum(ns2); nt2 = wave_sum(nt2);
    float ns = sqrtf(ns2), nt = sqrtf(nt2);
    float ds = fmaxf(ns, 1e-6f), dt = fmaxf(nt, 1e-6f);
    float uu[8], qq[8], wv[8];
#pragma unroll
    for (int i = 0; i < 8; ++i) { uu[i] = s[i] / ds; qq[i] = t[i] / dt; wv[i] = uu[i] + qq[i]; }
    float w2 = 0.f;
#pragma unroll
    for (int i = 0; i < 8; ++i) w2 += wv[i] * wv[i];
    w2 = wave_sum(w2);
    float wn = fmaxf(sqrtf(w2), 1e-12f);
#pragma unroll
    for (int i = 0; i < 8; ++i) wv[i] /= wn;
    float ew = 0.f, eu = 0.f;
#pragma unroll
    for (int i = 0; i < 8; ++i) { ew += s[i] * wv[i]; eu += s[i] * uu[i]; }
    ew = wave_sum(ew); eu = wave_sum(eu);
    const float scale = nt / ds;
    float r[8];
    float lacc = 0.f;
#pragma unroll
    for (int i = 0; i < 8; ++i) {
        r[i] = (s[i] - 2.f * ew * wv[i] + 2.f * eu * qq[i]) * scale;
        float d = s[i] - t[i];
        lacc += d * d;
    }
    float* op = outq + (size_t)row * DIMV + lane * 8;
    *(float4*)op = make_float4(r[0], r[1], r[2], r[3]);
    *(float4*)(op + 4) = make_float4(r[4], r[5], r[6], r[7]);
    lacc = wave_sum(lacc);
    if (lane == 0) atomicAdd(lossp, lacc);
}

// K5: finalize: (mean + 0.25*mean) * 1.0 = 1.25 * sum / (B*N*D)
__global__ void k5_loss(const float* __restrict__ lossp, float* __restrict__ outl) {
    outl[0] = lossp[0] * 1.25f / 16777216.0f;
}

extern "C" void kernel_launch(void* const* d_in, const int* in_sizes, int n_in,
                              void* d_out, int out_size, void* d_ws, size_t ws_size,
                              hipStream_t stream) {
    const float* x  = (const float*)d_in[0];   // (8,4096,512) f32
    const float* W  = (const float*)d_in[1];   // (512,512) f32
    const float* cb = (const float*)d_in[2];   // (8192,512) f32
    float* out = (float*)d_out;
    float* out_q = out;                        // 16,777,216 f32
    float* out_i = out + 16777216;             // 32,768 f32 (indices as values)
    float* out_l = out + 16777216 + 32768;     // 1 f32 (commit loss)

    float* ws = (float*)d_ws;
    float* cbn = ws;                                    // 8192*512 f32 (16 MiB)
    int* idxp = (int*)(ws + (size_t)CBSZ * DIMV);       // 32768 int
    float* lossp = ws + (size_t)CBSZ * DIMV + MROWS;    // 1 f32

    hipMemsetAsync(lossp, 0, sizeof(float), stream);
    k1_implicit<<<dim3(CBSZ / 64, DIMV / 64), 256, 0, stream>>>(cb, W, cbn);
    k2_normrows<<<CBSZ / 4, 256, 0, stream>>>(cbn);
    k3_argmax<<<MROWS / 64, 512, 0, stream>>>(x, cbn, idxp, out_i);
    k4_rotate<<<MROWS / 4, 256, 0, stream>>>(x, cbn, idxp, out_q, lossp);
    k5_loss<<<1, 1, 0, stream>>>(lossp, out_l);
}

// Round 4
// 1765.420 us; speedup vs baseline: 3.2684x; 3.2684x over previous
//
#include <hip/hip_runtime.h>

typedef unsigned int u32;
typedef unsigned short u16;
typedef __attribute__((ext_vector_type(8))) short short8;
typedef __attribute__((ext_vector_type(4))) float f32x4;

#define CBSZ 8192
#define DIMV 512
#define MROWS 32768   // 8*4096
#define CAP 40
#define DELTA 0.125f

__device__ __forceinline__ u16 f2bf(float f) {
    u32 u = __float_as_uint(f);
    u32 r = (u + 0x7fffu + ((u >> 16) & 1u)) >> 16;   // RNE
    return (u16)r;
}

__device__ __forceinline__ float wave_sum(float v) {
#pragma unroll
    for (int m = 1; m < 64; m <<= 1) v += __shfl_xor(v, m);
    return v;
}

// monotone float <-> sortable u32
__device__ __forceinline__ u32 enc_f(float f) {
    u32 u = __float_as_uint(f);
    return (u & 0x80000000u) ? ~u : (u | 0x80000000u);
}
__device__ __forceinline__ float dec_f(u32 e) {
    return (e & 0x80000000u) ? __uint_as_float(e & 0x7FFFFFFFu) : __uint_as_float(~e);
}

// K1: implicit_cb[c][d] = sum_k cb[c][k] * W[d][k]   (fp32 GEMM, 64x64 tiles)
__global__ __launch_bounds__(256) void k1_implicit(const float* __restrict__ cb,
                                                   const float* __restrict__ W,
                                                   float* __restrict__ outp) {
    __shared__ float As[64 * 64];
    __shared__ float Bs[64 * 64];
    const int c0 = blockIdx.x * 64, d0 = blockIdx.y * 64;
    const int tid = threadIdx.x;
    const int tx = tid & 15, ty = tid >> 4;
    float acc[4][4] = {};
    for (int k0 = 0; k0 < DIMV; k0 += 64) {
        __syncthreads();
#pragma unroll
        for (int it = 0; it < 4; ++it) {
            int chunk = tid + 256 * it;
            int row = chunk >> 4;
            int g = chunk & 15;
            int gs = (g ^ (row & 15)) * 4;
            *(float4*)&As[row * 64 + gs] =
                *(const float4*)(cb + (size_t)(c0 + row) * DIMV + k0 + g * 4);
            *(float4*)&Bs[row * 64 + gs] =
                *(const float4*)(W + (size_t)(d0 + row) * DIMV + k0 + g * 4);
        }
        __syncthreads();
#pragma unroll
        for (int k = 0; k < 64; k += 4) {
            const int g = k >> 2;
            float4 a[4], b[4];
#pragma unroll
            for (int i = 0; i < 4; ++i) a[i] = *(float4*)&As[(ty + 16 * i) * 64 + ((g ^ ty) * 4)];
#pragma unroll
            for (int j = 0; j < 4; ++j) b[j] = *(float4*)&Bs[(tx + 16 * j) * 64 + ((g ^ tx) * 4)];
#pragma unroll
            for (int i = 0; i < 4; ++i)
#pragma unroll
                for (int j = 0; j < 4; ++j) {
                    acc[i][j] = fmaf(a[i].x, b[j].x, acc[i][j]);
                    acc[i][j] = fmaf(a[i].y, b[j].y, acc[i][j]);
                    acc[i][j] = fmaf(a[i].z, b[j].z, acc[i][j]);
                    acc[i][j] = fmaf(a[i].w, b[j].w, acc[i][j]);
                }
        }
    }
#pragma unroll
    for (int i = 0; i < 4; ++i)
#pragma unroll
        for (int j = 0; j < 4; ++j)
            outp[(size_t)(c0 + ty + 16 * i) * DIMV + d0 + tx + 16 * j] = acc[i][j];
}

// K2: in-place row l2norm of cbn (8192x512 f32) + write bf16 copy cbb.
__global__ __launch_bounds__(256) void k2_normrows(float* __restrict__ cbn,
                                                   u16* __restrict__ cbb) {
    const int row = blockIdx.x * 4 + (threadIdx.x >> 6);
    const int lane = threadIdx.x & 63;
    float* p = cbn + (size_t)row * DIMV + lane * 8;
    float4 v0 = *(float4*)p, v1 = *(float4*)(p + 4);
    float ss = v0.x * v0.x + v0.y * v0.y + v0.z * v0.z + v0.w * v0.w
             + v1.x * v1.x + v1.y * v1.y + v1.z * v1.z + v1.w * v1.w;
    ss = wave_sum(ss);
    float n = fmaxf(sqrtf(ss), 1e-12f);
    v0.x /= n; v0.y /= n; v0.z /= n; v0.w /= n;
    v1.x /= n; v1.y /= n; v1.z /= n; v1.w /= n;
    *(float4*)p = v0;
    *(float4*)(p + 4) = v1;
    u32 p0 = (u32)f2bf(v0.x) | ((u32)f2bf(v0.y) << 16);
    u32 p1 = (u32)f2bf(v0.z) | ((u32)f2bf(v0.w) << 16);
    u32 p2 = (u32)f2bf(v1.x) | ((u32)f2bf(v1.y) << 16);
    u32 p3 = (u32)f2bf(v1.z) | ((u32)f2bf(v1.w) << 16);
    *(uint4*)(cbb + (size_t)row * DIMV + lane * 8) = make_uint4(p0, p1, p2, p3);
}

// K3: bf16 MFMA prefilter. Block = 64 rows x all 8192 codes (chunks of 128).
// LDS tiles in fragment-linear order: block (g,s) of 1024B holds lane L's
// b128 frag at offset (g*4+s)*1024 + L*16 (A: m=L&15, k=s*32+(L>>4)*8).
// Per-row prefix max (ordered-u32 atomicMax) + candidates within DELTA.
__global__ __launch_bounds__(256, 2) void k3_scan(const float* __restrict__ x,
                                                  const u16* __restrict__ cbb,
                                                  u16* __restrict__ cand_g,
                                                  u32* __restrict__ cnt_g) {
    __shared__ __align__(16) u16 xs[64 * 128];     // 16 KB
    __shared__ __align__(16) u16 cbs[128 * 128];   // 32 KB
    __shared__ u32 pmax[64];
    __shared__ u32 cnt[64];
    __shared__ u16 cand[64 * CAP];

    const int tid = threadIdx.x;
    const int lane = tid & 63;
    const int w = tid >> 6;           // wave 0..3
    const int w_r = w >> 1, w_c = w & 1;   // wave quadrant: 32 rows x 64 codes
    const int r0 = blockIdx.x * 64;

    if (tid < 64) { pmax[tid] = 0x007FFFFFu; cnt[tid] = 0; }   // enc(-inf), 0
    __syncthreads();

    for (int ct = 0; ct < CBSZ; ct += 128) {
        f32x4 acc[2][4] = {};
        for (int kc = 0; kc < 4; ++kc) {       // K chunks of 128
            __syncthreads();                   // prev reads done before overwrite
            // stage xs: f32 -> bf16 (truncate), fragment-linear
#pragma unroll
            for (int i = 0; i < 4; ++i) {
                int q = tid + 256 * i;         // 0..1023
                int l = q & 63;
                int gs = q >> 6;               // g = gs>>2 (0..3), s = gs&3
                int row = (gs >> 2) * 16 + (l & 15);
                int k = kc * 128 + (gs & 3) * 32 + (l >> 4) * 8;
                const float* gp = x + (size_t)(r0 + row) * DIMV + k;
                float4 v0 = *(const float4*)gp;
                float4 v1 = *(const float4*)(gp + 4);
                u32 p0 = (__float_as_uint(v0.y) & 0xFFFF0000u) | (__float_as_uint(v0.x) >> 16);
                u32 p1 = (__float_as_uint(v0.w) & 0xFFFF0000u) | (__float_as_uint(v0.z) >> 16);
                u32 p2 = (__float_as_uint(v1.y) & 0xFFFF0000u) | (__float_as_uint(v1.x) >> 16);
                u32 p3 = (__float_as_uint(v1.w) & 0xFFFF0000u) | (__float_as_uint(v1.z) >> 16);
                *(uint4*)&xs[gs * 512 + l * 8] = make_uint4(p0, p1, p2, p3);
            }
            // stage cbs: bf16 copy, fragment-linear
#pragma unroll
            for (int i = 0; i < 8; ++i) {
                int q = tid + 256 * i;         // 0..2047
                int l = q & 63;
                int gs = q >> 6;               // g' = gs>>2 (0..7), s = gs&3
                int code = ct + (gs >> 2) * 16 + (l & 15);
                int k = kc * 128 + (gs & 3) * 32 + (l >> 4) * 8;
                uint4 v = *(const uint4*)(cbb + (size_t)code * DIMV + k);
                *(uint4*)&cbs[gs * 512 + l * 8] = v;
            }
            __syncthreads();
#pragma unroll
            for (int s = 0; s < 4; ++s) {
                short8 a[2], b[4];
#pragma unroll
                for (int t = 0; t < 2; ++t)
                    a[t] = *(const short8*)&xs[(((w_r * 2 + t) * 4 + s) * 512) + lane * 8];
#pragma unroll
                for (int u = 0; u < 4; ++u)
                    b[u] = *(const short8*)&cbs[(((w_c * 4 + u) * 4 + s) * 512) + lane * 8];
#pragma unroll
                for (int t = 0; t < 2; ++t)
#pragma unroll
                    for (int u = 0; u < 4; ++u)
                        acc[t][u] = __builtin_amdgcn_mfma_f32_16x16x32_bf16(a[t], b[u], acc[t][u], 0, 0, 0);
            }
        }
        // --- candidate phase ---
        // update prefix max (per row)
#pragma unroll
        for (int t = 0; t < 2; ++t)
#pragma unroll
            for (int r = 0; r < 4; ++r) {
                float m = fmaxf(fmaxf(acc[t][0][r], acc[t][1][r]),
                                fmaxf(acc[t][2][r], acc[t][3][r]));
#pragma unroll
                for (int msk = 1; msk < 16; msk <<= 1) m = fmaxf(m, __shfl_xor(m, msk));
                if ((lane & 15) == 0) {
                    int rl = w_r * 32 + t * 16 + (lane >> 4) * 4 + r;
                    atomicMax(&pmax[rl], enc_f(m));
                }
            }
        __syncthreads();
        // collect candidates within DELTA of prefix max (incl. this chunk)
#pragma unroll
        for (int t = 0; t < 2; ++t)
#pragma unroll
            for (int r = 0; r < 4; ++r) {
                int rl = w_r * 32 + t * 16 + (lane >> 4) * 4 + r;
                float thr = dec_f(pmax[rl]) - DELTA;
#pragma unroll
                for (int u = 0; u < 4; ++u) {
                    if (acc[t][u][r] >= thr) {
                        u32 p = atomicAdd(&cnt[rl], 1u);
                        int code = ct + w_c * 64 + u * 16 + (lane & 15);
                        if (p < CAP) cand[rl * CAP + p] = (u16)code;
                    }
                }
            }
        // next chunk's first __syncthreads orders pushes before pmax updates
    }
    __syncthreads();
    if (tid < 64) cnt_g[r0 + tid] = cnt[tid];
    for (int i = tid; i < 64 * CAP; i += 256)
        cand_g[(size_t)r0 * CAP + i] = cand[i];
}

// K3b: fp64 rescore of candidates (raw dot, scale-invariant), first-max tie rule.
__global__ __launch_bounds__(256) void k3b_rescore(const float* __restrict__ x,
                                                   const float* __restrict__ cbn,
                                                   const u16* __restrict__ cand_g,
                                                   const u32* __restrict__ cnt_g,
                                                   int* __restrict__ idxp,
                                                   float* __restrict__ out_idx) {
    const int row = blockIdx.x * 4 + (threadIdx.x >> 6);
    const int lane = threadIdx.x & 63;
    const float* xr = x + (size_t)row * DIMV + lane * 8;
    float4 a0 = *(const float4*)xr, a1 = *(const float4*)(xr + 4);
    double xd[8] = {a0.x, a0.y, a0.z, a0.w, a1.x, a1.y, a1.z, a1.w};
    u32 nc = cnt_g[row];
    double best = -1e300;
    int bi = CBSZ;
    if (nc <= CAP) {
        for (u32 i = 0; i < nc; ++i) {
            int c = cand_g[(size_t)row * CAP + i];
            const float* cp = cbn + (size_t)c * DIMV + lane * 8;
            float4 c0 = *(const float4*)cp, c1 = *(const float4*)(cp + 4);
            double d = xd[0] * c0.x + xd[1] * c0.y + xd[2] * c0.z + xd[3] * c0.w
                     + xd[4] * c1.x + xd[5] * c1.y + xd[6] * c1.z + xd[7] * c1.w;
#pragma unroll
            for (int m = 1; m < 64; m <<= 1) d += __shfl_xor(d, m);
            if (d > best || (d == best && c < bi)) { best = d; bi = c; }
        }
    } else {
        // overflow fallback (statistically never): exact full scan
        for (int c = 0; c < CBSZ; ++c) {
            const float* cp = cbn + (size_t)c * DIMV + lane * 8;
            float4 c0 = *(const float4*)cp, c1 = *(const float4*)(cp + 4);
            double d = xd[0] * c0.x + xd[1] * c0.y + xd[2] * c0.z + xd[3] * c0.w
                     + xd[4] * c1.x + xd[5] * c1.y + xd[6] * c1.z + xd[7] * c1.w;
#pragma unroll
            for (int m = 1; m < 64; m <<= 1) d += __shfl_xor(d, m);
            if (d > best || (d == best && c < bi)) { best = d; bi = c; }
        }
    }
    if (lane == 0) { idxp[row] = bi; out_idx[row] = (float)bi; }
}

// K4: per-row gather + rotation trick + commit-loss partial. One wave per row.
__global__ __launch_bounds__(256) void k4_rotate(const float* __restrict__ x,
                                                 const float* __restrict__ cbn,
                                                 const int* __restrict__ idxp,
                                                 float* __restrict__ outq,
                                                 float* __restrict__ lossp) {
    const int row = blockIdx.x * 4 + (threadIdx.x >> 6);
    const int lane = threadIdx.x & 63;
    const float* xp = x + (size_t)row * DIMV + lane * 8;
    float4 a0 = *(const float4*)xp, a1 = *(const float4*)(xp + 4);
    float xf[8] = {a0.x, a0.y, a0.z, a0.w, a1.x, a1.y, a1.z, a1.w};
    float ss = 0.f;
#pragma unroll
    for (int i = 0; i < 8; ++i) ss += xf[i] * xf[i];
    ss = wave_sum(ss);
    float nx = fmaxf(sqrtf(ss), 1e-12f);
    float s[8];
#pragma unroll
    for (int i = 0; i < 8; ++i) s[i] = xf[i] / nx;
    int ci = idxp[row];
    ci = ci < 0 ? 0 : (ci > CBSZ - 1 ? CBSZ - 1 : ci);
    const float* tp = cbn + (size_t)ci * DIMV + lane * 8;
    float4 t0 = *(const float4*)tp, t1 = *(const float4*)(tp + 4);
    float t[8] = {t0.x, t0.y, t0.z, t0.w, t1.x, t1.y, t1.z, t1.w};
    float ns2 = 0.f, nt2 = 0.f;
#pragma unroll
    for (int i = 0; i < 8; ++i) { ns2 += s[i] * s[i]; nt2 += t[i] * t[i]; }
    ns2 = wave_sum(ns2); nt2 = wave_sum(nt2);
    float ns = sqrtf(ns2), nt = sqrtf(nt2);
    float ds = fmaxf(ns, 1e-6f), dt = fmaxf(nt, 1e-6f);
    float uu[8], qq[8], wv[8];
#pragma unroll
    for (int i = 0; i < 8; ++i) { uu[i] = s[i] / ds; qq[i] = t[i] / dt; wv[i] = uu[i] + qq[i]; }
    float w2 = 0.f;
#pragma unroll
    for (int i = 0; i < 8; ++i) w2 += wv[i] * wv[i];
    w2 = wave_sum(w2);
    float wn = fmaxf(sqrtf(w2), 1e-12f);
#pragma unroll
    for (int i = 0; i < 8; ++i) wv[i] /= wn;
    float ew = 0.f, eu = 0.f;
#pragma unroll
    for (int i = 0; i < 8; ++i) { ew += s[i] * wv[i]; eu += s[i] * uu[i]; }
    ew = wave_sum(ew); eu = wave_sum(eu);
    const float scale = nt / ds;
    float r[8];
    float lacc = 0.f;
#pragma unroll
    for (int i = 0; i < 8; ++i) {
        r[i] = (s[i] - 2.f * ew * wv[i] + 2.f * eu * qq[i]) * scale;
        float d = s[i] - t[i];
        lacc += d * d;
    }
    float* op = outq + (size_t)row * DIMV + lane * 8;
    *(float4*)op = make_float4(r[0], r[1], r[2], r[3]);
    *(float4*)(op + 4) = make_float4(r[4], r[5], r[6], r[7]);
    lacc = wave_sum(lacc);
    if (lane == 0) atomicAdd(lossp, lacc);
}

// K5: finalize: 1.25 * sum / (B*N*D)
__global__ void k5_loss(const float* __restrict__ lossp, float* __restrict__ outl) {
    outl[0] = lossp[0] * 1.25f / 16777216.0f;
}

extern "C" void kernel_launch(void* const* d_in, const int* in_sizes, int n_in,
                              void* d_out, int out_size, void* d_ws, size_t ws_size,
                              hipStream_t stream) {
    const float* x  = (const float*)d_in[0];   // (8,4096,512) f32
    const float* W  = (const float*)d_in[1];   // (512,512) f32
    const float* cb = (const float*)d_in[2];   // (8192,512) f32
    float* out = (float*)d_out;
    float* out_q = out;                        // 16,777,216 f32
    float* out_i = out + 16777216;             // 32,768 f32
    float* out_l = out + 16777216 + 32768;     // 1 f32

    float* ws = (float*)d_ws;
    float* cbn = ws;                                           // 4,194,304 f32
    u16*   cbb = (u16*)(ws + (size_t)CBSZ * DIMV);             // 4,194,304 u16
    float* base2 = ws + (size_t)CBSZ * DIMV + (size_t)CBSZ * DIMV / 2;
    u16*   cand_g = (u16*)base2;                               // 32768*CAP u16
    float* base3 = base2 + (size_t)MROWS * CAP / 2;
    u32*   cnt_g = (u32*)base3;                                // 32768 u32
    int*   idxp  = (int*)(base3 + MROWS);                      // 32768 int
    float* lossp = base3 + 2 * MROWS;                          // 1 f32

    hipMemsetAsync(lossp, 0, sizeof(float), stream);
    k1_implicit<<<dim3(CBSZ / 64, DIMV / 64), 256, 0, stream>>>(cb, W, cbn);
    k2_normrows<<<CBSZ / 4, 256, 0, stream>>>(cbn, cbb);
    k3_scan<<<MROWS / 64, 256, 0, stream>>>(x, cbb, cand_g, cnt_g);
    k3b_rescore<<<MROWS / 4, 256, 0, stream>>>(x, cbn, cand_g, cnt_g, idxp, out_i);
    k4_rotate<<<MROWS / 4, 256, 0, stream>>>(x, cbn, idxp, out_q, lossp);
    k5_loss<<<1, 1, 0, stream>>>(lossp, out_l);
}